// Round 2
// baseline (322.356 us; speedup 1.0000x reference)
//
#include <hip/hip_runtime.h>

// LeakyZOPlainOnce: 32-step LIF scan with LocalZO straight-through surrogate.
// inputs:  d_in[0] = x  (T*B*F fp32), d_in[1] = z (same shape)
// output:  d_out    = spikes (T*B*F fp32)
//
// R1 notes:
//  - VEC=2: 8192 waves -> 32 waves/CU (VEC=4 capped occupancy at 50%).
//  - 1-deep prefetch: loads for t+1 issued before compute of t, so the
//    compiler can wait with vmcnt(N>0) instead of a full drain each iter.
//  - nontemporal stores: output stream (134 MB) must not evict the
//    LLC-resident inputs (268 MB ~ LLC size); R0 showed FETCH == half the
//    inputs, i.e. write allocation evicted them.
//
// Determinism: spike = (h - surr*v) + surr*v is NOT exactly h when
// surr*v > 2 (residual ~1e-6 feeds the u recurrence), so the fp32 op order
// replicates numpy exactly: separate mul+add (fp contract off), true IEEE
// division by 0.1f, strict comparisons. R0 passed with absmax 0.0.

constexpr int BATCH = 128;
constexpr int FDIM  = 8192;
constexpr int STEP  = BATCH * FDIM;   // elements per time step = 1,048,576
constexpr int VEC   = 2;              // floats per thread per step

typedef float f32x2 __attribute__((ext_vector_type(2)));

__device__ __forceinline__ float lif_step(float& u, float xs, float zs)
{
    float uu = 0.5f * u;          // beta * u   (separate mul + add)
    uu = uu + xs;
    float v = uu - 1.0f;          // u - u_th
    float az   = fabsf(zs);
    float ind  = (fabsf(v) < 0.05f * az) ? 1.0f : 0.0f;
    float surr = (az / 0.1f) * ind;
    float h    = (v > 0.0f) ? 1.0f : 0.0f;
    float a     = surr * v;
    float spike = (h - a) + a;    // straight-through forward
    u = uu - spike * 1.0f;        // soft reset
    return spike;
}

__global__ __launch_bounds__(256) void lif_zo_kernel(
    const float* __restrict__ x,
    const float* __restrict__ z,
    float* __restrict__ out,
    int T)
{
#pragma clang fp contract(off)
    const int tid = blockIdx.x * blockDim.x + threadIdx.x;
    long idx = (long)tid * VEC;

    float u0 = 0.0f, u1 = 0.0f;

    // prologue: loads for t=0
    f32x2 xt = *reinterpret_cast<const f32x2*>(x + idx);
    f32x2 zt = *reinterpret_cast<const f32x2*>(z + idx);

    for (int t = 0; t < T; ++t) {
        // prefetch t+1 (clamped address on last iter; wave-uniform, no branch)
        const long nidx = idx + ((t + 1 < T) ? (long)STEP : 0);
        f32x2 xn = *reinterpret_cast<const f32x2*>(x + nidx);
        f32x2 zn = *reinterpret_cast<const f32x2*>(z + nidx);

        f32x2 s;
        s.x = lif_step(u0, xt.x, zt.x);
        s.y = lif_step(u1, xt.y, zt.y);

        __builtin_nontemporal_store(s, reinterpret_cast<f32x2*>(out + idx));

        idx = idx + STEP;
        xt = xn;
        zt = zn;
    }
}

extern "C" void kernel_launch(void* const* d_in, const int* in_sizes, int n_in,
                              void* d_out, int out_size, void* d_ws, size_t ws_size,
                              hipStream_t stream)
{
    const float* x = (const float*)d_in[0];
    const float* z = (const float*)d_in[1];
    float* out = (float*)d_out;

    const int total = in_sizes[0];          // T * B * F
    const int T = total / STEP;             // = 32 for this problem

    const int nthreads = STEP / VEC;        // 524,288
    const int block = 256;
    const int grid = nthreads / block;      // 2048

    lif_zo_kernel<<<grid, block, 0, stream>>>(x, z, out, T);
}